// Round 1
// 232.081 us; speedup vs baseline: 1.0164x; 1.0164x over previous
//
#include <hip/hip_runtime.h>

// BilateralGrid apply. R1: LDS fp16 grid gather (118 us). R2: packed fp16
// v_pk_fma_f16 interpolation (103 us/dispatch) — rocprof: VALU 24%, HBM 22%,
// SQ_LDS_BANK_CONFLICT 3.2e7 (~10 extra cy per ds_read_b64 gather = ~52 us/CU
// of stall). Root cause: start bank = (16*(x0&1) + 6*z0) mod 32 — y stride
// (3072 B) contributes 0 mod 32, and z0 (guide luminance) concentrates in
// {2,3,4}, so ~68% of lanes start on ~6 banks.
// R3: bank-decorrelating padded layout. Keep Zstride=12 halves (z0/z1 pair
// must stay contiguous for the 48 B/corner read), pad Xstride 96->100 halves
// (200 B == 9 mod 16 in 8B units), Ystride 1536->1604 halves (3208 B == 1
// mod 16). Start bank becomes (y0 + 9*x0 + 3*z0) mod 16 with y0,x0 uniform
// -> ~uniform over all 16 even start positions. 50.1 KB LDS, still 3
// blocks/CU. Numerics unchanged.

typedef _Float16 h2 __attribute__((ext_vector_type(2)));
typedef _Float16 h4 __attribute__((ext_vector_type(4)));

#define BLOCK 512
// Padded LDS strides (in halves / fp16 elements).
#define ZS 12      // z stride: 24 B (contiguous z-pair reads)
#define XS 100     // x stride: 8*12 + 4 pad = 200 B  (== 9 mod 16 in 8B units)
#define YS 1604    // y stride: 16*100 + 4 pad = 3208 B (== 1 mod 16 in 8B units)
#define NLDS (16 * YS)   // 25664 halves = 51328 B

__global__ __launch_bounds__(BLOCK) void bilateral_apply(
    const float* __restrict__ pixels,
    const float* __restrict__ coords,
    const float* __restrict__ grid,
    float* __restrict__ out,
    int n4)
{
    __shared__ _Float16 gl[NLDS];  // 50.1 KB

    // Cooperative stage: fp32 grid -> fp16 LDS, swizzled layout.
    // 2048 cells of 12 coeffs; cell = ((y*16)+x)*8+z in the source.
    {
        for (int cell = threadIdx.x; cell < 2048; cell += BLOCK) {
            int y = cell >> 7;
            int x = (cell >> 3) & 15;
            int z = cell & 7;
            const float4* src = (const float4*)(grid + (long long)cell * 12);
            float4 v0 = src[0], v1 = src[1], v2 = src[2];
            h4* d = (h4*)(gl + y * YS + x * XS + z * ZS);  // 8 B aligned
            d[0] = h4{(_Float16)v0.x, (_Float16)v0.y, (_Float16)v0.z, (_Float16)v0.w};
            d[1] = h4{(_Float16)v1.x, (_Float16)v1.y, (_Float16)v1.z, (_Float16)v1.w};
            d[2] = h4{(_Float16)v2.x, (_Float16)v2.y, (_Float16)v2.z, (_Float16)v2.w};
        }
    }
    __syncthreads();

    const int stride = gridDim.x * BLOCK;
    for (int t = blockIdx.x * BLOCK + threadIdx.x; t < n4; t += stride) {
        long long base = (long long)t * 4;  // first pixel of this quad

        const float* pp = pixels + base * 3;
        const float* cp = coords + base * 2;
        float4 pa = *(const float4*)(pp + 0);
        float4 pb = *(const float4*)(pp + 4);
        float4 pc = *(const float4*)(pp + 8);
        float4 ca = *(const float4*)(cp + 0);
        float4 cb = *(const float4*)(cp + 4);

        float R[4]  = {pa.x, pa.w, pb.z, pc.y};
        float G[4]  = {pa.y, pb.x, pb.w, pc.z};
        float Bc[4] = {pa.z, pb.y, pc.x, pc.w};
        float CX[4] = {ca.x, ca.z, cb.x, cb.z};
        float CY[4] = {ca.y, ca.w, cb.y, cb.w};

        float O[12];

        #pragma unroll
        for (int k = 0; k < 4; ++k) {
            float r = R[k], g = G[k], b = Bc[k];
            float guide = 0.2126f * r + 0.7152f * g + 0.0722f * b;

            float gx = fminf(fmaxf(CX[k] * 15.0f, 0.0f), 14.999f);
            float gy = fminf(fmaxf(CY[k] * 15.0f, 0.0f), 14.999f);
            float gz = fminf(fminf(fmaxf(guide, 0.0f), 1.0f) * 7.0f, 6.999f);

            int x0 = (int)gx, y0 = (int)gy, z0 = (int)gz;
            float fx = gx - (float)x0;
            float fy = gy - (float)y0;
            float fz = gz - (float)z0;

            int cbase = y0 * YS + x0 * XS + z0 * ZS;
            const int coff[4] = {0, XS, YS, YS + XS};  // (y0,x0),(y0,x1),(y1,x0),(y1,x1)
            float wz0 = 1.0f - fz, wz1 = fz;
            float cw[4] = {(1.0f - fy) * (1.0f - fx), (1.0f - fy) * fx,
                           fy * (1.0f - fx),           fy * fx};

            h4 acc0 = (h4)(_Float16)0.0f;
            h4 acc1 = (h4)(_Float16)0.0f;
            h4 acc2 = (h4)(_Float16)0.0f;

            #pragma unroll
            for (int c = 0; c < 4; ++c) {
                const h4* q = (const h4*)(gl + cbase + coff[c]);  // 8-B aligned
                h4 a0 = q[0], a1 = q[1], a2 = q[2];  // z0 plane (12 vals)
                h4 b0 = q[3], b1 = q[4], b2 = q[5];  // z1 plane
                _Float16 u0 = (_Float16)(cw[c] * wz0);
                _Float16 u1 = (_Float16)(cw[c] * wz1);
                h4 u0v = {u0, u0, u0, u0};
                h4 u1v = {u1, u1, u1, u1};
                // acc = a*u0 + (b*u1 + acc)  -> v_pk_fma_f16 pairs
                acc0 = a0 * u0v + (b0 * u1v + acc0);
                acc1 = a1 * u0v + (b1 * u1v + acc1);
                acc2 = a2 * u0v + (b2 * u1v + acc2);
            }

            O[3 * k + 0] = fmaf((float)acc0.x, r, fmaf((float)acc0.y, g,
                           fmaf((float)acc0.z, b, (float)acc0.w)));
            O[3 * k + 1] = fmaf((float)acc1.x, r, fmaf((float)acc1.y, g,
                           fmaf((float)acc1.z, b, (float)acc1.w)));
            O[3 * k + 2] = fmaf((float)acc2.x, r, fmaf((float)acc2.y, g,
                           fmaf((float)acc2.z, b, (float)acc2.w)));
        }

        float* op = out + base * 3;
        *(float4*)(op + 0) = make_float4(O[0], O[1], O[2],  O[3]);
        *(float4*)(op + 4) = make_float4(O[4], O[5], O[6],  O[7]);
        *(float4*)(op + 8) = make_float4(O[8], O[9], O[10], O[11]);
    }
}

extern "C" void kernel_launch(void* const* d_in, const int* in_sizes, int n_in,
                              void* d_out, int out_size, void* d_ws, size_t ws_size,
                              hipStream_t stream) {
    const float* pixels = (const float*)d_in[0];
    const float* coords = (const float*)d_in[1];
    const float* grid   = (const float*)d_in[2];
    float* out = (float*)d_out;

    int npix = in_sizes[0] / 3;   // 8,294,400 (divisible by 4)
    int n4   = npix / 4;          // 2,073,600 quads
    // 50.1 KB LDS/block, 512 thr => 3 blocks/CU (24 waves). 768 = 3*256 CUs.
    int nblk = 768;
    bilateral_apply<<<nblk, BLOCK, 0, stream>>>(pixels, coords, grid, out, n4);
}